// Round 2
// baseline (261.253 us; speedup 1.0000x reference)
//
#include <hip/hip_runtime.h>
#include <hip/hip_bf16.h>
#include <stdint.h>

// Int4Linear: out[M,N] = X[M,K] @ W[N,K]^T + bias,  W = (q - zp)*scale
// M = 2*2048 = 4096, N = 4096, K = 4096.  fp32 in/out, bf16 MFMA compute.

#define MDIM 4096
#define NDIM 4096
#define KDIM 4096
#define BM 128
#define BN 128
#define BK 32
#define NT (KDIM / BK)

typedef __attribute__((ext_vector_type(8))) short     bf16x8;
typedef __attribute__((ext_vector_type(4))) float     f32x4;
typedef __attribute__((ext_vector_type(8))) unsigned short u16x8;

__device__ __forceinline__ unsigned short f32_bf16_rne(float f) {
  union { float f; unsigned u; } v; v.f = f;
  return (unsigned short)((v.u + 0x7FFFu + ((v.u >> 16) & 1u)) >> 16);
}

// ---- x fp32 -> bf16, 8 elems/thread, vectorized ----
__global__ __launch_bounds__(256) void cvt_x_kernel(const float* __restrict__ x,
                                                    unsigned short* __restrict__ xb) {
  int i = blockIdx.x * 256 + threadIdx.x;
  const f32x4* p = (const f32x4*)x + (size_t)i * 2;
  f32x4 a = p[0], b = p[1];
  u16x8 o;
  o[0] = f32_bf16_rne(a[0]); o[1] = f32_bf16_rne(a[1]);
  o[2] = f32_bf16_rne(a[2]); o[3] = f32_bf16_rne(a[3]);
  o[4] = f32_bf16_rne(b[0]); o[5] = f32_bf16_rne(b[1]);
  o[6] = f32_bf16_rne(b[2]); o[7] = f32_bf16_rne(b[3]);
  *((u16x8*)xb + i) = o;
}

// ---- W dequant: (q - zp[o]) * scale[o] -> bf16, 8 elems/thread ----
__global__ __launch_bounds__(256) void dequant_w_kernel(const int* __restrict__ q,
                                                        const float* __restrict__ scale,
                                                        const int* __restrict__ zp,
                                                        unsigned short* __restrict__ wb) {
  int i = blockIdx.x * 256 + threadIdx.x;   // granule of 8 along a row
  int o = i >> 9;                           // 4096/8 = 512 granules per row
  float s = scale[o];
  float z = (float)zp[o];
  const int4* p = (const int4*)q + (size_t)i * 2;
  int4 a = p[0], b = p[1];
  u16x8 r;
  r[0] = f32_bf16_rne(((float)a.x - z) * s);
  r[1] = f32_bf16_rne(((float)a.y - z) * s);
  r[2] = f32_bf16_rne(((float)a.z - z) * s);
  r[3] = f32_bf16_rne(((float)a.w - z) * s);
  r[4] = f32_bf16_rne(((float)b.x - z) * s);
  r[5] = f32_bf16_rne(((float)b.y - z) * s);
  r[6] = f32_bf16_rne(((float)b.z - z) * s);
  r[7] = f32_bf16_rne(((float)b.w - z) * s);
  *((u16x8*)wb + i) = r;
}

// ---- GEMM: m97 structure. 128x128 tile, BK=32, 4 waves 2x2, dbuf LDS via
// global_load_lds width 16 (linear LDS layout), 2-barrier K-loop. ----
__global__ __launch_bounds__(256) void gemm_kernel(const unsigned short* __restrict__ A,
                                                   const unsigned short* __restrict__ B,
                                                   const float* __restrict__ bias,
                                                   float* __restrict__ C) {
  __shared__ __align__(16) unsigned short sA[2][BM * BK];
  __shared__ __align__(16) unsigned short sB[2][BN * BK];

  // XCD-bijective swizzle (nwg = 1024, divisible by 8)
  const int nwg = (MDIM / BM) * (NDIM / BN);
  const int cpx = nwg >> 3;
  int bid = (int)blockIdx.x;
  int wg  = (bid & 7) * cpx + (bid >> 3);
  int bm  = wg >> 5;                 // NDIM/BN = 32
  int bn  = wg & 31;

  const int tid  = threadIdx.x;
  const int lane = tid & 63;
  const int wave = tid >> 6;
  const int wm   = wave >> 1;
  const int wn   = wave & 1;
  const int lr   = lane & 15;        // fragment row (A) / col (B,D)
  const int lk   = lane >> 4;        // k-group 0..3

  const size_t rowA0 = (size_t)bm * BM;
  const size_t rowB0 = (size_t)bn * BN;

  f32x4 acc[4][4];
#pragma unroll
  for (int m = 0; m < 4; ++m)
#pragma unroll
    for (int n = 0; n < 4; ++n) acc[m][n] = (f32x4)0.f;

  auto stage = [&](int buf, int kt) {
#pragma unroll
    for (int i = 0; i < 2; ++i) {
      int li = i * 256 + tid;        // 16B granule index, 0..511
      int r  = li >> 2;              // tile row
      int cb = (li & 3) * 16;        // byte offset within 64B row
      const char* gA = (const char*)(A + (rowA0 + r) * KDIM + (size_t)kt * BK) + cb;
      __builtin_amdgcn_global_load_lds((const __attribute__((address_space(1))) void*)gA,
                                       (__attribute__((address_space(3))) void*)(&sA[buf][li * 8]),
                                       16, 0, 0);
      const char* gB = (const char*)(B + (rowB0 + r) * KDIM + (size_t)kt * BK) + cb;
      __builtin_amdgcn_global_load_lds((const __attribute__((address_space(1))) void*)gB,
                                       (__attribute__((address_space(3))) void*)(&sB[buf][li * 8]),
                                       16, 0, 0);
    }
  };

  stage(0, 0);
  __syncthreads();   // drains vmcnt(0) before barrier

  int cur = 0;
  for (int kt = 0; kt < NT; ++kt) {
    if (kt + 1 < NT) stage(cur ^ 1, kt + 1);

    bf16x8 af[4], bfr[4];
#pragma unroll
    for (int m = 0; m < 4; ++m)
      af[m] = *(const bf16x8*)&sA[cur][(wm * 64 + m * 16 + lr) * BK + lk * 8];
#pragma unroll
    for (int n = 0; n < 4; ++n)
      bfr[n] = *(const bf16x8*)&sB[cur][(wn * 64 + n * 16 + lr) * BK + lk * 8];

#pragma unroll
    for (int m = 0; m < 4; ++m)
#pragma unroll
      for (int n = 0; n < 4; ++n)
        acc[m][n] = __builtin_amdgcn_mfma_f32_16x16x32_bf16(af[m], bfr[n], acc[m][n], 0, 0, 0);

    __syncthreads();   // all ds_reads of cur done; staged cur^1 landed
    cur ^= 1;
  }

  // Epilogue: D(row = lk*4 + reg, col = lr) per 16x16 fragment; add bias.
  const size_t crow0 = rowA0 + (size_t)wm * 64;
  const size_t ccol0 = rowB0 + (size_t)wn * 64;
#pragma unroll
  for (int n = 0; n < 4; ++n) {
    size_t col = ccol0 + n * 16 + lr;
    float bv = bias[col];
#pragma unroll
    for (int m = 0; m < 4; ++m) {
      size_t row = crow0 + m * 16 + lk * 4;
#pragma unroll
      for (int r = 0; r < 4; ++r)
        C[(row + r) * NDIM + col] = acc[m][n][r] + bv;
    }
  }
}

extern "C" void kernel_launch(void* const* d_in, const int* in_sizes, int n_in,
                              void* d_out, int out_size, void* d_ws, size_t ws_size,
                              hipStream_t stream) {
  const float* x     = (const float*)d_in[0];
  const int*   qw    = (const int*)d_in[1];
  const float* scale = (const float*)d_in[2];
  const int*   zp    = (const int*)d_in[3];
  const float* bias  = (const float*)d_in[4];
  float* out = (float*)d_out;

  unsigned short* xb = (unsigned short*)d_ws;                 // 4096*4096 bf16 = 32 MiB
  unsigned short* wb = xb + (size_t)MDIM * KDIM;              // +32 MiB

  const int n8 = MDIM * KDIM / 8;   // 2M granules
  cvt_x_kernel<<<n8 / 256, 256, 0, stream>>>(x, xb);
  dequant_w_kernel<<<n8 / 256, 256, 0, stream>>>(qw, scale, zp, wb);
  gemm_kernel<<<1024, 256, 0, stream>>>(xb, wb, bias, out);
}

// Round 3
// 160.026 us; speedup vs baseline: 1.6326x; 1.6326x over previous
//
#include <hip/hip_runtime.h>
#include <hip/hip_bf16.h>
#include <stdint.h>

// Int4Linear: out[M,N] = X[M,K] @ W[N,K]^T + bias,  W = (q - zp)*scale
// M = 4096, N = 4096, K = 4096.  fp32 in/out, bf16 MFMA compute.
// GEMM: 256x256 tile, BK=64, 8 waves (2M x 4N), 8-phase schedule with
// counted vmcnt + LDS XOR swizzle + setprio (guide SS5 template, adapted).

#define MDIM 4096
#define NDIM 4096
#define KDIM 4096
#define BM 256
#define BN 256
#define BK 64
#define NT (KDIM / BK)   // 64 K-tiles

typedef __attribute__((ext_vector_type(8))) short          bf16x8;
typedef __attribute__((ext_vector_type(4))) float          f32x4;
typedef __attribute__((ext_vector_type(8))) unsigned short u16x8;

__device__ __forceinline__ unsigned short f32_bf16_rne(float f) {
  union { float f; unsigned u; } v; v.f = f;
  return (unsigned short)((v.u + 0x7FFFu + ((v.u >> 16) & 1u)) >> 16);
}

// ---- x fp32 -> bf16, 8 elems/thread ----
__global__ __launch_bounds__(256) void cvt_x_kernel(const float* __restrict__ x,
                                                    unsigned short* __restrict__ xb) {
  int i = blockIdx.x * 256 + threadIdx.x;
  const f32x4* p = (const f32x4*)x + (size_t)i * 2;
  f32x4 a = p[0], b = p[1];
  u16x8 o;
  o[0] = f32_bf16_rne(a[0]); o[1] = f32_bf16_rne(a[1]);
  o[2] = f32_bf16_rne(a[2]); o[3] = f32_bf16_rne(a[3]);
  o[4] = f32_bf16_rne(b[0]); o[5] = f32_bf16_rne(b[1]);
  o[6] = f32_bf16_rne(b[2]); o[7] = f32_bf16_rne(b[3]);
  *((u16x8*)xb + i) = o;
}

// ---- W dequant: (q - zp[o]) * scale[o] -> bf16, 8 elems/thread ----
__global__ __launch_bounds__(256) void dequant_w_kernel(const int* __restrict__ q,
                                                        const float* __restrict__ scale,
                                                        const int* __restrict__ zp,
                                                        unsigned short* __restrict__ wb) {
  int i = blockIdx.x * 256 + threadIdx.x;
  int o = i >> 9;
  float s = scale[o];
  float z = (float)zp[o];
  const int4* p = (const int4*)q + (size_t)i * 2;
  int4 a = p[0], b = p[1];
  u16x8 r;
  r[0] = f32_bf16_rne(((float)a.x - z) * s);
  r[1] = f32_bf16_rne(((float)a.y - z) * s);
  r[2] = f32_bf16_rne(((float)a.z - z) * s);
  r[3] = f32_bf16_rne(((float)a.w - z) * s);
  r[4] = f32_bf16_rne(((float)b.x - z) * s);
  r[5] = f32_bf16_rne(((float)b.y - z) * s);
  r[6] = f32_bf16_rne(((float)b.z - z) * s);
  r[7] = f32_bf16_rne(((float)b.w - z) * s);
  *((u16x8*)wb + i) = r;
}

#define BAR() { asm volatile("" ::: "memory"); __builtin_amdgcn_s_barrier(); asm volatile("" ::: "memory"); }
#define LGKM0() asm volatile("s_waitcnt lgkmcnt(0)" ::: "memory")

#define MFMA_Q(MH, NH)                                                          \
  { __builtin_amdgcn_s_setprio(1);                                              \
    _Pragma("unroll") for (int fm = 0; fm < 4; ++fm)                            \
    _Pragma("unroll") for (int fn = 0; fn < 2; ++fn)                            \
    _Pragma("unroll") for (int ks = 0; ks < 2; ++ks)                            \
      acc[MH][NH][fm][fn] = __builtin_amdgcn_mfma_f32_16x16x32_bf16(            \
          aR[MH][fm][ks], bR[fn][ks], acc[MH][NH][fm][fn], 0, 0, 0);            \
    __builtin_amdgcn_s_setprio(0); }

// LDS map (byte offsets into 128 KiB):
//   A: (buf*2 + half) * 16384            [0, 64K)
//   B: 65536 + (buf*2 + half) * 16384    [64K, 128K)
// half-tile = 128 rows x 64 bf16 = 16 KiB. Swizzle involution on byte offset
// within a half-tile: o ^= ((o>>7)&7)<<4  (spreads 8 rows over all banks).
__global__ __launch_bounds__(512, 2) void gemm_kernel(const unsigned short* __restrict__ A,
                                                      const unsigned short* __restrict__ B,
                                                      const float* __restrict__ bias,
                                                      float* __restrict__ C) {
  __shared__ __align__(16) char lds[131072];

  // XCD-bijective swizzle: nwg = 256, divisible by 8
  int bid = (int)blockIdx.x;
  int wg  = (bid & 7) * 32 + (bid >> 3);
  int bm  = wg >> 4;                // 16 tiles per row
  int bn  = wg & 15;

  const int tid   = threadIdx.x;
  const int lane  = tid & 63;
  const int wv    = tid >> 6;       // 0..7
  const int wm    = wv >> 2;        // 0..1
  const int wn    = wv & 3;         // 0..3
  const int lr    = lane & 15;
  const int kg    = lane >> 4;      // 0..3
  const int bhalf = wn >> 1;        // B half-tile this wave reads
  const int brow0 = (wn & 1) * 64;  // local row base within that B half

  const size_t rowA0 = (size_t)bm * BM;
  const size_t rowB0 = (size_t)bn * BN;

  f32x4 acc[2][2][4][2];            // [mh][nh][fm][fn]
#pragma unroll
  for (int a = 0; a < 2; ++a)
#pragma unroll
    for (int b = 0; b < 2; ++b)
#pragma unroll
      for (int c = 0; c < 4; ++c)
#pragma unroll
        for (int d = 0; d < 2; ++d) acc[a][b][c][d] = (f32x4)0.f;

  bf16x8 aR[2][4][2];               // [mh][fm][ks] — both M-halves kept live
  bf16x8 bR[2][2];                  // [fn][ks]     — current N-half only

  // stage one half-tile (2 x global_load_lds per thread, linear LDS dest,
  // inverse-swizzled global source)
  auto stage = [&](const unsigned short* G, size_t row0, int kt, int half, int matBase) {
    int ldsBase = matBase + ((kt & 1) * 2 + half) * 16384;
#pragma unroll
    for (int i = 0; i < 2; ++i) {
      int L  = tid * 16 + i * 8192;
      int o  = L ^ (((L >> 7) & 7) << 4);
      int r  = o >> 7;
      int cb = o & 127;
      const char* src = (const char*)G +
          ((row0 + half * 128 + r) * (size_t)KDIM + (size_t)kt * BK) * 2 + cb;
      __builtin_amdgcn_global_load_lds((const __attribute__((address_space(1))) void*)src,
                                       (__attribute__((address_space(3))) void*)(lds + ldsBase + L),
                                       16, 0, 0);
    }
  };

  auto ldsA = [&](int cur, int mh, int fm, int ks) -> bf16x8 {
    int ra  = mh * 64 + fm * 16 + lr;
    int off = (ra << 7) + ks * 64 + kg * 16;
    off ^= (ra & 7) << 4;
    return *(const bf16x8*)(lds + (cur * 2 + wm) * 16384 + off);
  };
  auto ldsB = [&](int cur, int nh, int fn, int ks) -> bf16x8 {
    int rb  = brow0 + nh * 32 + fn * 16 + lr;
    int off = (rb << 7) + ks * 64 + kg * 16;
    off ^= (rb & 7) << 4;
    return *(const bf16x8*)(lds + 65536 + (cur * 2 + bhalf) * 16384 + off);
  };

  // ---- prologue: K0 fully + A-halves of K1; wait first 8 loads (K0) ----
  stage(A, rowA0, 0, 0, 0);
  stage(A, rowA0, 0, 1, 0);
  stage(B, rowB0, 0, 0, 65536);
  stage(B, rowB0, 0, 1, 65536);
  stage(A, rowA0, 1, 0, 0);
  stage(A, rowA0, 1, 1, 0);
  asm volatile("s_waitcnt vmcnt(4)" ::: "memory");
  BAR();

  // ---- main loop: 4 phases per K-tile ----
  for (int u = 0; u < NT; ++u) {
    int cur = u & 1;

    // Q1 (mh=0, nh=0): load A M-half0 (8 reads) + B N-half0 (4 reads); stage B.h0(u+1)
#pragma unroll
    for (int fm = 0; fm < 4; ++fm)
#pragma unroll
      for (int ks = 0; ks < 2; ++ks) aR[0][fm][ks] = ldsA(cur, 0, fm, ks);
#pragma unroll
    for (int fn = 0; fn < 2; ++fn)
#pragma unroll
      for (int ks = 0; ks < 2; ++ks) bR[fn][ks] = ldsB(cur, 0, fn, ks);
    if (u + 1 < NT) stage(B, rowB0, u + 1, 0, 65536);
    BAR(); LGKM0(); MFMA_Q(0, 0); BAR();

    // Q2 (mh=1, nh=0): load A M-half1 (8 reads); stage B.h1(u+1)
#pragma unroll
    for (int fm = 0; fm < 4; ++fm)
#pragma unroll
      for (int ks = 0; ks < 2; ++ks) aR[1][fm][ks] = ldsA(cur, 1, fm, ks);
    if (u + 1 < NT) stage(B, rowB0, u + 1, 1, 65536);
    BAR(); LGKM0(); MFMA_Q(1, 0); BAR();

    // Q3 (mh=1, nh=1): load B N-half1 (4 reads); stage A.h0(u+2)
#pragma unroll
    for (int fn = 0; fn < 2; ++fn)
#pragma unroll
      for (int ks = 0; ks < 2; ++ks) bR[fn][ks] = ldsB(cur, 1, fn, ks);
    if (u + 2 < NT) stage(A, rowA0, u + 2, 0, 0);
    BAR(); LGKM0(); MFMA_Q(1, 1); BAR();

    // Q4 (mh=0, nh=1): no ds_reads (aR[0], bR reused); stage A.h1(u+2); vmcnt
    if (u + 2 < NT) stage(A, rowA0, u + 2, 1, 0);
    if (u < NT - 2)       { asm volatile("s_waitcnt vmcnt(4)" ::: "memory"); }
    else if (u == NT - 2) { asm volatile("s_waitcnt vmcnt(0)" ::: "memory"); }
    BAR(); MFMA_Q(0, 1); BAR();
  }

  // ---- epilogue: D col = lane&15, row = (lane>>4)*4 + reg; add bias ----
  const size_t crow0 = rowA0 + (size_t)wm * 128;
  const size_t ccol0 = rowB0 + (size_t)wn * 64;
#pragma unroll
  for (int nh = 0; nh < 2; ++nh)
#pragma unroll
    for (int fn = 0; fn < 2; ++fn) {
      size_t col = ccol0 + nh * 32 + fn * 16 + lr;
      float bv = bias[col];
#pragma unroll
      for (int mh = 0; mh < 2; ++mh)
#pragma unroll
        for (int fm = 0; fm < 4; ++fm) {
          size_t row = crow0 + mh * 64 + fm * 16 + kg * 4;
#pragma unroll
          for (int r = 0; r < 4; ++r)
            C[(row + r) * NDIM + col] = acc[mh][nh][fm][fn][r] + bv;
        }
    }
}

extern "C" void kernel_launch(void* const* d_in, const int* in_sizes, int n_in,
                              void* d_out, int out_size, void* d_ws, size_t ws_size,
                              hipStream_t stream) {
  const float* x     = (const float*)d_in[0];
  const int*   qw    = (const int*)d_in[1];
  const float* scale = (const float*)d_in[2];
  const int*   zp    = (const int*)d_in[3];
  const float* bias  = (const float*)d_in[4];
  float* out = (float*)d_out;

  unsigned short* xb = (unsigned short*)d_ws;            // 32 MiB
  unsigned short* wb = xb + (size_t)MDIM * KDIM;         // +32 MiB

  const int n8 = MDIM * KDIM / 8;
  cvt_x_kernel<<<n8 / 256, 256, 0, stream>>>(x, xb);
  dequant_w_kernel<<<n8 / 256, 256, 0, stream>>>(qw, scale, zp, wb);
  gemm_kernel<<<(MDIM / BM) * (NDIM / BN), 512, 0, stream>>>(xb, wb, bias, out);
}

// Round 6
// 148.637 us; speedup vs baseline: 1.7577x; 1.0766x over previous
//
#include <hip/hip_runtime.h>
#include <hip/hip_bf16.h>
#include <stdint.h>

// Int4Linear: out[M,N] = X[M,K] @ W[N,K]^T + bias,  W = (q - zp)*scale
// M = 4096, N = 4096, K = 4096.  fp32 in/out, bf16 MFMA compute.
// GEMM: 256x256 tile, BK=64, 8 waves (2M x 4N), 4 phases/K-tile,
// ONE barrier per phase (pre-MFMA), counted vmcnt, LDS XOR swizzle, setprio.

#define MDIM 4096
#define NDIM 4096
#define KDIM 4096
#define BM 256
#define BN 256
#define BK 64
#define NT (KDIM / BK)   // 64 K-tiles

typedef __attribute__((ext_vector_type(8))) short          bf16x8;
typedef __attribute__((ext_vector_type(4))) float          f32x4;
typedef __attribute__((ext_vector_type(8))) unsigned short u16x8;

__device__ __forceinline__ unsigned short f32_bf16_rne(float f) {
  union { float f; unsigned u; } v; v.f = f;
  return (unsigned short)((v.u + 0x7FFFu + ((v.u >> 16) & 1u)) >> 16);
}

// ---- x fp32 -> bf16, 8 elems/thread ----
__global__ __launch_bounds__(256) void cvt_x_kernel(const float* __restrict__ x,
                                                    unsigned short* __restrict__ xb) {
  int i = blockIdx.x * 256 + threadIdx.x;
  const f32x4* p = (const f32x4*)x + (size_t)i * 2;
  f32x4 a = p[0], b = p[1];
  u16x8 o;
  o[0] = f32_bf16_rne(a[0]); o[1] = f32_bf16_rne(a[1]);
  o[2] = f32_bf16_rne(a[2]); o[3] = f32_bf16_rne(a[3]);
  o[4] = f32_bf16_rne(b[0]); o[5] = f32_bf16_rne(b[1]);
  o[6] = f32_bf16_rne(b[2]); o[7] = f32_bf16_rne(b[3]);
  *((u16x8*)xb + i) = o;
}

// ---- W dequant: (q - zp[o]) * scale[o] -> bf16, 8 elems/thread ----
__global__ __launch_bounds__(256) void dequant_w_kernel(const int* __restrict__ q,
                                                        const float* __restrict__ scale,
                                                        const int* __restrict__ zp,
                                                        unsigned short* __restrict__ wb) {
  int i = blockIdx.x * 256 + threadIdx.x;
  int o = i >> 9;
  float s = scale[o];
  float z = (float)zp[o];
  const int4* p = (const int4*)q + (size_t)i * 2;
  int4 a = p[0], b = p[1];
  u16x8 r;
  r[0] = f32_bf16_rne(((float)a.x - z) * s);
  r[1] = f32_bf16_rne(((float)a.y - z) * s);
  r[2] = f32_bf16_rne(((float)a.z - z) * s);
  r[3] = f32_bf16_rne(((float)a.w - z) * s);
  r[4] = f32_bf16_rne(((float)b.x - z) * s);
  r[5] = f32_bf16_rne(((float)b.y - z) * s);
  r[6] = f32_bf16_rne(((float)b.z - z) * s);
  r[7] = f32_bf16_rne(((float)b.w - z) * s);
  *((u16x8*)wb + i) = r;
}

#define BAR() { asm volatile("" ::: "memory"); __builtin_amdgcn_s_barrier(); asm volatile("" ::: "memory"); }

// ks OUTER: the 8 MFMAs of ks=0 are mutually independent; the dependent
// accumulator re-use (ks=1) is 8 instructions away -> fully pipelined.
#define MFMA_Q(MH, NH)                                                          \
  { __builtin_amdgcn_s_setprio(1);                                              \
    _Pragma("unroll") for (int ks = 0; ks < 2; ++ks)                            \
    _Pragma("unroll") for (int fm = 0; fm < 4; ++fm)                            \
    _Pragma("unroll") for (int fn = 0; fn < 2; ++fn)                            \
      acc[MH][NH][fm][fn] = __builtin_amdgcn_mfma_f32_16x16x32_bf16(            \
          aR[MH][fm][ks], bR[fn][ks], acc[MH][NH][fm][fn], 0, 0, 0);            \
    __builtin_amdgcn_s_setprio(0); }

// LDS map (byte offsets into 128 KiB):
//   A: (buf*2 + half) * 16384            [0, 64K)
//   B: 65536 + (buf*2 + half) * 16384    [64K, 128K)
// half-tile = 128 rows x 64 bf16 = 16 KiB. Swizzle involution on byte offset
// within a half-tile: o ^= ((o>>7)&7)<<4.
__global__ __launch_bounds__(512, 2) void gemm_kernel(const unsigned short* __restrict__ A,
                                                      const unsigned short* __restrict__ B,
                                                      const float* __restrict__ bias,
                                                      float* __restrict__ C) {
  __shared__ __align__(16) char lds[131072];

  // XCD-bijective swizzle: nwg = 256, divisible by 8
  int bid = (int)blockIdx.x;
  int wg  = (bid & 7) * 32 + (bid >> 3);
  int bm  = wg >> 4;                // 16 tiles per row
  int bn  = wg & 15;

  const int tid   = threadIdx.x;
  const int lane  = tid & 63;
  const int wv    = tid >> 6;       // 0..7
  const int wm    = wv >> 2;        // 0..1
  const int wn    = wv & 3;         // 0..3
  const int lr    = lane & 15;
  const int kg    = lane >> 4;      // 0..3
  const int bhalf = wn >> 1;        // B half-tile this wave reads
  const int brow0 = (wn & 1) * 64;  // local row base within that B half

  const size_t rowA0 = (size_t)bm * BM;
  const size_t rowB0 = (size_t)bn * BN;

  f32x4 acc[2][2][4][2];            // [mh][nh][fm][fn]
#pragma unroll
  for (int a = 0; a < 2; ++a)
#pragma unroll
    for (int b = 0; b < 2; ++b)
#pragma unroll
      for (int c = 0; c < 4; ++c)
#pragma unroll
        for (int d = 0; d < 2; ++d) acc[a][b][c][d] = (f32x4)0.f;

  bf16x8 aR[2][4][2];               // [mh][fm][ks]
  bf16x8 bR[2][2];                  // [fn][ks]

  auto stage = [&](const unsigned short* G, size_t row0, int kt, int half, int matBase) {
    int ldsBase = matBase + ((kt & 1) * 2 + half) * 16384;
#pragma unroll
    for (int i = 0; i < 2; ++i) {
      int L  = tid * 16 + i * 8192;
      int o  = L ^ (((L >> 7) & 7) << 4);
      int r  = o >> 7;
      int cb = o & 127;
      const char* src = (const char*)G +
          ((row0 + half * 128 + r) * (size_t)KDIM + (size_t)kt * BK) * 2 + cb;
      __builtin_amdgcn_global_load_lds((const __attribute__((address_space(1))) void*)src,
                                       (__attribute__((address_space(3))) void*)(lds + ldsBase + L),
                                       16, 0, 0);
    }
  };

  auto ldsA = [&](int cur, int mh, int fm, int ks) -> bf16x8 {
    int ra  = mh * 64 + fm * 16 + lr;
    int off = (ra << 7) + ks * 64 + kg * 16;
    off ^= (ra & 7) << 4;
    return *(const bf16x8*)(lds + (cur * 2 + wm) * 16384 + off);
  };
  auto ldsB = [&](int cur, int nh, int fn, int ks) -> bf16x8 {
    int rb  = brow0 + nh * 32 + fn * 16 + lr;
    int off = (rb << 7) + ks * 64 + kg * 16;
    off ^= (rb & 7) << 4;
    return *(const bf16x8*)(lds + 65536 + (cur * 2 + bhalf) * 16384 + off);
  };

  // ---- prologue: K0 fully + A-halves of K1; drain K0 (8 oldest of 12) ----
  stage(A, rowA0, 0, 0, 0);
  stage(A, rowA0, 0, 1, 0);
  stage(B, rowB0, 0, 0, 65536);
  stage(B, rowB0, 0, 1, 65536);
  stage(A, rowA0, 1, 0, 0);
  stage(A, rowA0, 1, 1, 0);
  asm volatile("s_waitcnt vmcnt(4)" ::: "memory");
  BAR();

  // ---- main loop: 4 phases per K-tile, ONE barrier per phase ----
  for (int u = 0; u < NT; ++u) {
    int cur = u & 1;

    // Q1 (mh=0,nh=0): reads A.h0 (8) + B.h0 (4) interleaved ks-major; stage B.h0(u+1)
#pragma unroll
    for (int ks = 0; ks < 2; ++ks) {
#pragma unroll
      for (int fm = 0; fm < 4; ++fm) aR[0][fm][ks] = ldsA(cur, 0, fm, ks);
#pragma unroll
      for (int fn = 0; fn < 2; ++fn) bR[fn][ks] = ldsB(cur, 0, fn, ks);
    }
    if (u + 1 < NT) stage(B, rowB0, u + 1, 0, 65536);
    BAR(); MFMA_Q(0, 0);

    // Q2 (mh=1,nh=0): reads A.h1 (8); stage B.h1(u+1)
#pragma unroll
    for (int ks = 0; ks < 2; ++ks)
#pragma unroll
      for (int fm = 0; fm < 4; ++fm) aR[1][fm][ks] = ldsA(cur, 1, fm, ks);
    if (u + 1 < NT) stage(B, rowB0, u + 1, 1, 65536);
    BAR(); MFMA_Q(1, 0);

    // Q3 (mh=1,nh=1): reads B.h1 (4); stage A.h0(u+2)
#pragma unroll
    for (int ks = 0; ks < 2; ++ks)
#pragma unroll
      for (int fn = 0; fn < 2; ++fn) bR[fn][ks] = ldsB(cur, 1, fn, ks);
    if (u + 2 < NT) stage(A, rowA0, u + 2, 0, 0);
    BAR(); MFMA_Q(1, 1);

    // Q4 (mh=0,nh=1): no reads; stage A.h1(u+2); counted vmcnt once per K-tile
    if (u + 2 < NT) stage(A, rowA0, u + 2, 1, 0);
    if (u < NT - 2)       { asm volatile("s_waitcnt vmcnt(4)" ::: "memory"); }
    else if (u == NT - 2) { asm volatile("s_waitcnt vmcnt(0)" ::: "memory"); }
    BAR(); MFMA_Q(0, 1);
  }

  // ---- epilogue: D col = lane&15, row = (lane>>4)*4 + reg; add bias ----
  const size_t crow0 = rowA0 + (size_t)wm * 128;
  const size_t ccol0 = rowB0 + (size_t)wn * 64;
#pragma unroll
  for (int nh = 0; nh < 2; ++nh)
#pragma unroll
    for (int fn = 0; fn < 2; ++fn) {
      size_t col = ccol0 + nh * 32 + fn * 16 + lr;
      float bv = bias[col];
#pragma unroll
      for (int mh = 0; mh < 2; ++mh)
#pragma unroll
        for (int fm = 0; fm < 4; ++fm) {
          size_t row = crow0 + mh * 64 + fm * 16 + kg * 4;
#pragma unroll
          for (int r = 0; r < 4; ++r)
            C[(row + r) * NDIM + col] = acc[mh][nh][fm][fn][r] + bv;
        }
    }
}

extern "C" void kernel_launch(void* const* d_in, const int* in_sizes, int n_in,
                              void* d_out, int out_size, void* d_ws, size_t ws_size,
                              hipStream_t stream) {
  const float* x     = (const float*)d_in[0];
  const int*   qw    = (const int*)d_in[1];
  const float* scale = (const float*)d_in[2];
  const int*   zp    = (const int*)d_in[3];
  const float* bias  = (const float*)d_in[4];
  float* out = (float*)d_out;

  unsigned short* xb = (unsigned short*)d_ws;            // 32 MiB
  unsigned short* wb = xb + (size_t)MDIM * KDIM;         // +32 MiB

  const int n8 = MDIM * KDIM / 8;
  cvt_x_kernel<<<n8 / 256, 256, 0, stream>>>(x, xb);
  dequant_w_kernel<<<n8 / 256, 256, 0, stream>>>(qw, scale, zp, wb);
  gemm_kernel<<<(MDIM / BM) * (NDIM / BN), 512, 0, stream>>>(xb, wb, bias, out);
}